// Round 2
// baseline (1628.759 us; speedup 1.0000x reference)
//
#include <hip/hip_runtime.h>
#include <hip/hip_bf16.h>
#include <stdint.h>
#include <stddef.h>

using bf16 = __hip_bfloat16;
typedef __attribute__((ext_vector_type(8))) short short8;   // 8 bf16 (4 VGPRs)
typedef __attribute__((ext_vector_type(4))) float f32x4;

#define T_TOK 2048
#define HD    2048
#define NH    32
#define NKV   16
#define DKh   128
#define DVh   128

// ---------- helpers ----------
__device__ __forceinline__ void bf2f(uint32_t u, float& a, float& b) {
    union { uint32_t i; float f; } x;
    x.i = u << 16;          a = x.f;   // low  half = element 0
    x.i = u & 0xffff0000u;  b = x.f;   // high half = element 1
}

__device__ __forceinline__ void gload16(const void* g, void* l) {
    __builtin_amdgcn_global_load_lds(
        (const __attribute__((address_space(1))) void*)g,
        (__attribute__((address_space(3))) void*)l, 16, 0, 0);
}

__device__ __forceinline__ void store_c(bf16* C, size_t off, float v) { C[off] = __float2bfloat16(v); }
__device__ __forceinline__ void store_c(float* C, size_t off, float v) { C[off] = v; }

// ---------- convert fp32 -> bf16 elementwise ----------
__global__ __launch_bounds__(256) void f2b_kernel(
    const float* __restrict__ in, bf16* __restrict__ out, int n)
{
    int i = blockIdx.x * 256 + threadIdx.x;
    if (i < n) out[i] = __float2bfloat16(in[i]);
}

// ---------- transpose+convert: in fp32 [R][C] -> out bf16 [C][R] ----------
__global__ __launch_bounds__(256) void transpose_kernel(
    const float* __restrict__ in, bf16* __restrict__ out, int R, int C)
{
    __shared__ bf16 tile[32][33];
    int c0 = blockIdx.x * 32, r0 = blockIdx.y * 32;
    int x = threadIdx.x;      // 0..31
    int y = threadIdx.y;      // 0..7
    #pragma unroll
    for (int i = y; i < 32; i += 8)
        tile[i][x] = __float2bfloat16(in[(size_t)(r0 + i) * C + c0 + x]);
    __syncthreads();
    #pragma unroll
    for (int i = y; i < 32; i += 8)
        out[(size_t)(c0 + i) * R + r0 + x] = tile[x][i];
}

// ---------- build [Wa|Wb|0] transposed: out bf16 [128][2048] ----------
__global__ __launch_bounds__(256) void build_wab_kernel(
    const float* __restrict__ Wa, const float* __restrict__ Wb, bf16* __restrict__ out)
{
    int k = blockIdx.x * 256 + threadIdx.x;  // 0..2047
    int n = blockIdx.y;                      // 0..127
    float v = 0.f;
    if (n < 32)      v = Wa[(size_t)k * 32 + n];
    else if (n < 64) v = Wb[(size_t)k * 32 + (n - 32)];
    out[(size_t)n * 2048 + k] = __float2bfloat16(v);
}

// ---------- MFMA GEMM: C[M,N] = A[M,K] * B^T (B given as [N,K]), bf16 in ----------
// 128x128 tile, BK=64, 4 waves, 4x4 16x16x32 MFMA per wave, global_load_lds
// staging with XOR chunk swizzle (chunk c of row r stored at position c^(r&7)).
template <typename OutT>
__global__ __launch_bounds__(256) void gemm_bt_kernel(
    const bf16* __restrict__ A, const bf16* __restrict__ B, OutT* __restrict__ C,
    int M, int N, int K)
{
    __shared__ short sA[128 * 64];
    __shared__ short sB[128 * 64];
    const int tid  = threadIdx.x;
    const int w    = tid >> 6;
    const int lane = tid & 63;
    const int quad = lane >> 4;
    const int r    = lane & 15;
    const int wm   = w >> 1, wn = w & 1;
    const int bm   = blockIdx.x, bn = blockIdx.y;
    const int lrow = lane >> 3;          // 0..7 row within 8-row staging group
    const int lp   = lane & 7;           // chunk position in LDS row
    const int lc   = lp ^ lrow;          // which global 16B chunk this lane fetches

    f32x4 acc[4][4] = {};

    const int nkb = K >> 6;
    for (int kb = 0; kb < nkb; ++kb) {
        __syncthreads();
        #pragma unroll
        for (int it = 0; it < 4; ++it) {
            int grp = w * 4 + it;                 // 0..15 (8 rows each)
            int rr  = grp * 8 + lrow;
            const bf16* ga = A + (size_t)(bm * 128 + rr) * K + kb * 64 + lc * 8;
            gload16(ga, (void*)(sA + grp * 512));
            const bf16* gb = B + (size_t)(bn * 128 + rr) * K + kb * 64 + lc * 8;
            gload16(gb, (void*)(sB + grp * 512));
        }
        __syncthreads();   // vmcnt(0) drain before barrier covers global_load_lds

        #pragma unroll
        for (int kk = 0; kk < 2; ++kk) {
            short8 av[4], bv[4];
            #pragma unroll
            for (int i = 0; i < 4; ++i) {
                int p   = (kk * 4 + quad) ^ (r & 7);
                int row = wm * 64 + i * 16 + r;
                av[i] = *(const short8*)(sA + row * 64 + p * 8);
                int rowb = wn * 64 + i * 16 + r;
                bv[i] = *(const short8*)(sB + rowb * 64 + p * 8);
            }
            #pragma unroll
            for (int i = 0; i < 4; ++i)
                #pragma unroll
                for (int j = 0; j < 4; ++j)
                    acc[i][j] = __builtin_amdgcn_mfma_f32_16x16x32_bf16(
                        av[i], bv[j], acc[i][j], 0, 0, 0);
        }
    }

    // epilogue: C/D layout col=lane&15, row=quad*4+reg  (m89-verified)
    #pragma unroll
    for (int i = 0; i < 4; ++i) {
        int row0 = bm * 128 + wm * 64 + i * 16 + quad * 4;
        #pragma unroll
        for (int j = 0; j < 4; ++j) {
            int col = bn * 128 + wn * 64 + j * 16 + r;
            #pragma unroll
            for (int e = 0; e < 4; ++e)
                store_c(C, (size_t)(row0 + e) * N + col, acc[i][j][e]);
        }
    }
}

// ---------- conv+silu+l2norm for q,k ----------
// grid (T, 32): g<16 -> q head g, else k head g-16. block 128 (one per dim).
__global__ __launch_bounds__(128) void conv_qk_kernel(
    const bf16* __restrict__ mixed, const float* __restrict__ cq,
    const float* __restrict__ ck, bf16* __restrict__ qn, bf16* __restrict__ kn)
{
    int t = blockIdx.x;
    int g = blockIdx.y;
    int d = threadIdx.x;
    int isq = (g < NKV) ? 1 : 0;
    int h   = isq ? g : g - NKV;
    int cl  = h * DKh + d;                 // channel inside q (or k) block
    int c   = (isq ? 0 : 2048) + cl;       // channel in mixed
    const float* cw = isq ? cq : ck;
    float acc = 0.f;
    #pragma unroll
    for (int j = 0; j < 4; ++j) {
        int ts = t - 3 + j;
        if (ts >= 0)
            acc += __bfloat162float(mixed[(size_t)ts * 8192 + c]) * cw[cl * 4 + j];
    }
    float s = acc / (1.f + __expf(-acc));  // silu
    float ss = s * s;
    #pragma unroll
    for (int m = 1; m < 64; m <<= 1) ss += __shfl_xor(ss, m, 64);
    __shared__ float part[2];
    if ((threadIdx.x & 63) == 0) part[threadIdx.x >> 6] = ss;
    __syncthreads();
    float sum = part[0] + part[1];
    float rn = rsqrtf(sum + 1e-6f);
    float outv = s * rn;
    if (isq) outv *= 0.08838834764831845f;   // DK^-0.5 folded into q
    (isq ? qn : kn)[(size_t)t * 2048 + cl] = __float2bfloat16(outv);
}

// ---------- conv+silu for v ----------
__global__ __launch_bounds__(256) void conv_v_kernel(
    const bf16* __restrict__ mixed, const float* __restrict__ cv, bf16* __restrict__ vv)
{
    int idx = blockIdx.x * 256 + threadIdx.x;   // t*4096 + c
    int t = idx >> 12, c = idx & 4095;
    float acc = 0.f;
    #pragma unroll
    for (int j = 0; j < 4; ++j) {
        int ts = t - 3 + j;
        if (ts >= 0)
            acc += __bfloat162float(mixed[(size_t)ts * 8192 + 4096 + c]) * cv[c * 4 + j];
    }
    vv[idx] = __float2bfloat16(acc / (1.f + __expf(-acc)));
}

// ---------- gating: eg = exp(-exp(A_log)*softplus(a+dt_bias)), beta = sigmoid(b) ----------
__global__ __launch_bounds__(256) void gating_kernel(
    const float* __restrict__ ab, const float* __restrict__ dt_bias,
    const float* __restrict__ A_log, float* __restrict__ eg, float* __restrict__ beta)
{
    int i = blockIdx.x * 256 + threadIdx.x;  // t*32+h
    int t = i >> 5, h = i & 31;
    float a  = ab[(size_t)t * 128 + h] + dt_bias[h];
    float sp = (a <= 20.f) ? log1pf(__expf(a)) : a;
    float gg = -__expf(A_log[h]) * sp;
    eg[i] = __expf(gg);
    float b = ab[(size_t)t * 128 + 32 + h];
    beta[i] = 1.f / (1.f + __expf(-b));
}

// ---------- gated delta-rule recurrence ----------
// grid (32 heads, 8 dv-splits), block 256: thread = (dv_local = tid>>4, dkg = tid&15)
// owns S[dkg*8 .. +8][dv] in registers; 16-lane shfl_xor reductions for kv and o.
__global__ __launch_bounds__(256) void recur_kernel(
    const bf16* __restrict__ qn, const bf16* __restrict__ kn, const bf16* __restrict__ vv,
    const float* __restrict__ egb, const float* __restrict__ betab, bf16* __restrict__ o)
{
    int h   = blockIdx.x;
    int sp  = blockIdx.y;
    int tid = threadIdx.x;
    int dvl = tid >> 4;
    int dkg = tid & 15;
    int dv  = sp * 16 + dvl;
    int hkv = h >> 1;                       // GQA repeat-interleave

    __shared__ float s_eg[T_TOK];
    __shared__ float s_bt[T_TOK];
    for (int i = tid; i < T_TOK; i += 256) {
        s_eg[i] = egb[(size_t)i * NH + h];
        s_bt[i] = betab[(size_t)i * NH + h];
    }
    __syncthreads();

    float S[8] = {0.f, 0.f, 0.f, 0.f, 0.f, 0.f, 0.f, 0.f};
    const uint4* krow = (const uint4*)(kn + hkv * DKh + dkg * 8);
    const uint4* qrow = (const uint4*)(qn + hkv * DKh + dkg * 8);
    const bf16*  vp   = vv + h * DVh + dv;

    uint4 kc = krow[0], qc = qrow[0];
    float vc = __bfloat162float(vp[0]);

    for (int t = 0; t < T_TOK; ++t) {
        uint4 kf4 = {0, 0, 0, 0}, qf4 = {0, 0, 0, 0};
        float vn = 0.f;
        if (t + 1 < T_TOK) {                        // prefetch next step
            kf4 = krow[(size_t)(t + 1) * 256];
            qf4 = qrow[(size_t)(t + 1) * 256];
            vn  = __bfloat162float(vp[(size_t)(t + 1) * 4096]);
        }
        float egt = s_eg[t], bt = s_bt[t];
        float kf[8], qf[8];
        bf2f(kc.x, kf[0], kf[1]); bf2f(kc.y, kf[2], kf[3]);
        bf2f(kc.z, kf[4], kf[5]); bf2f(kc.w, kf[6], kf[7]);
        bf2f(qc.x, qf[0], qf[1]); bf2f(qc.y, qf[2], qf[3]);
        bf2f(qc.z, qf[4], qf[5]); bf2f(qc.w, qf[6], qf[7]);

        float kv = 0.f;
        #pragma unroll
        for (int j = 0; j < 8; ++j) { S[j] *= egt; kv += S[j] * kf[j]; }
        #pragma unroll
        for (int m = 1; m < 16; m <<= 1) kv += __shfl_xor(kv, m, 64);
        float dvv = bt * (vc - kv);
        float op = 0.f;
        #pragma unroll
        for (int j = 0; j < 8; ++j) { S[j] += kf[j] * dvv; op += qf[j] * S[j]; }
        #pragma unroll
        for (int m = 1; m < 16; m <<= 1) op += __shfl_xor(op, m, 64);
        if (dkg == 0)
            o[(size_t)t * 4096 + h * DVh + dv] = __float2bfloat16(op);
        kc = kf4; qc = qf4; vc = vn;
    }
}

// ---------- gated RMSNorm: og = o * rsqrt(mean(o^2)+1e-5) * w * silu(gate) ----------
__global__ __launch_bounds__(256) void normgate_kernel(
    const bf16* __restrict__ o, const bf16* __restrict__ gate,
    const float* __restrict__ w, bf16* __restrict__ og)
{
    int grp  = blockIdx.x * 4 + (threadIdx.x >> 6);  // t*32+h
    int lane = threadIdx.x & 63;
    int t = grp >> 5, h = grp & 31;
    size_t base = (size_t)t * 4096 + h * DVh;
    uint32_t uo = *(const uint32_t*)(o + base + lane * 2);
    float a, b; bf2f(uo, a, b);
    float ss = a * a + b * b;
    #pragma unroll
    for (int m = 1; m < 64; m <<= 1) ss += __shfl_xor(ss, m, 64);
    float rn = rsqrtf(ss * (1.f / 128.f) + 1e-5f);
    uint32_t ug = *(const uint32_t*)(gate + base + lane * 2);
    float ga, gb; bf2f(ug, ga, gb);
    float wa = w[lane * 2], wb = w[lane * 2 + 1];
    float oa = a * rn * wa * (ga / (1.f + __expf(-ga)));
    float ob = b * rn * wb * (gb / (1.f + __expf(-gb)));
    og[base + lane * 2]     = __float2bfloat16(oa);
    og[base + lane * 2 + 1] = __float2bfloat16(ob);
}

// ---------- launch ----------
extern "C" void kernel_launch(void* const* d_in, const int* in_sizes, int n_in,
                              void* d_out, int out_size, void* d_ws, size_t ws_size,
                              hipStream_t stream)
{
    const float* h       = (const float*)d_in[0];
    const float* Wq      = (const float*)d_in[1];
    const float* Wk      = (const float*)d_in[2];
    const float* Wv      = (const float*)d_in[3];
    const float* Wa      = (const float*)d_in[4];
    const float* Wb      = (const float*)d_in[5];
    const float* Wg      = (const float*)d_in[6];
    const float* conv_q  = (const float*)d_in[7];
    const float* conv_k  = (const float*)d_in[8];
    const float* conv_v  = (const float*)d_in[9];
    const float* dt_bias = (const float*)d_in[10];
    const float* A_log   = (const float*)d_in[11];
    const float* onw     = (const float*)d_in[12];
    const float* Wo      = (const float*)d_in[13];
    float* out = (float*)d_out;

    char* ws = (char*)d_ws;
    bf16* WqkvT = (bf16*)ws;                 ws += (size_t)8192 * 2048 * 2;   // 33.5 MB
    bf16* WgT   = (bf16*)ws;                 ws += (size_t)4096 * 2048 * 2;   // 16.8 MB
    bf16* WoT   = (bf16*)ws;                 ws += (size_t)2048 * 4096 * 2;   // 16.8 MB
    bf16* WabT  = (bf16*)ws;                 ws += (size_t)128 * 2048 * 2;
    bf16* hb    = (bf16*)ws;                 ws += (size_t)2048 * 2048 * 2;   // 8.4 MB
    bf16* mixed = (bf16*)ws;                 ws += (size_t)2048 * 8192 * 2;   // 33.5 MB
    float* ab   = (float*)ws;                ws += (size_t)2048 * 128 * 4;
    bf16* qnb   = (bf16*)ws;                 ws += (size_t)2048 * 2048 * 2;
    bf16* knb   = (bf16*)ws;                 ws += (size_t)2048 * 2048 * 2;
    bf16* vvb   = (bf16*)ws;                 ws += (size_t)2048 * 4096 * 2;
    float* eg   = (float*)ws;                ws += (size_t)2048 * 32 * 4;
    float* beta = (float*)ws;                ws += (size_t)2048 * 32 * 4;
    // aliases over dead regions (lifetimes are strictly ordered on the stream):
    bf16* ob   = WqkvT;                            // dead after qkv GEMM
    bf16* gate = WqkvT + (size_t)2048 * 4096;      // second half of WqkvT region
    bf16* og   = mixed;                            // mixed dead after conv kernels

    dim3 tb(32, 8);
    transpose_kernel<<<dim3(64, 64),  tb, 0, stream>>>(Wq, WqkvT,                         2048, 2048);
    transpose_kernel<<<dim3(64, 64),  tb, 0, stream>>>(Wk, WqkvT + (size_t)2048 * 2048,   2048, 2048);
    transpose_kernel<<<dim3(128, 64), tb, 0, stream>>>(Wv, WqkvT + (size_t)4096 * 2048,   2048, 4096);
    transpose_kernel<<<dim3(128, 64), tb, 0, stream>>>(Wg, WgT,                           2048, 4096);
    transpose_kernel<<<dim3(64, 128), tb, 0, stream>>>(Wo, WoT,                           4096, 2048);
    build_wab_kernel<<<dim3(8, 128), 256, 0, stream>>>(Wa, Wb, WabT);
    f2b_kernel<<<16384, 256, 0, stream>>>(h, hb, 2048 * 2048);

    gemm_bt_kernel<bf16> <<<dim3(16, 64), 256, 0, stream>>>(hb, WqkvT, mixed, 2048, 8192, 2048);
    gemm_bt_kernel<float><<<dim3(16, 1),  256, 0, stream>>>(hb, WabT,  ab,    2048, 128,  2048);
    gemm_bt_kernel<bf16> <<<dim3(16, 32), 256, 0, stream>>>(hb, WgT,   gate,  2048, 4096, 2048);

    conv_qk_kernel<<<dim3(2048, 32), 128, 0, stream>>>(mixed, conv_q, conv_k, qnb, knb);
    conv_v_kernel<<<32768, 256, 0, stream>>>(mixed, conv_v, vvb);
    gating_kernel<<<256, 256, 0, stream>>>(ab, dt_bias, A_log, eg, beta);

    recur_kernel<<<dim3(32, 8), 256, 0, stream>>>(qnb, knb, vvb, eg, beta, ob);
    normgate_kernel<<<16384, 256, 0, stream>>>(ob, gate, onw, og);

    gemm_bt_kernel<float><<<dim3(16, 16), 256, 0, stream>>>(og, WoT, out, 2048, 2048, 4096);
}

// Round 3
// 1240.111 us; speedup vs baseline: 1.3134x; 1.3134x over previous
//
#include <hip/hip_runtime.h>
#include <hip/hip_bf16.h>
#include <stdint.h>
#include <stddef.h>

using bf16 = __hip_bfloat16;
typedef __attribute__((ext_vector_type(8))) short short8;   // 8 bf16 (4 VGPRs)
typedef __attribute__((ext_vector_type(4))) float f32x4;

#define T_TOK 2048
#define HD    2048
#define NH    32
#define NKV   16
#define DKh   128
#define DVh   128

// ---------- helpers ----------
__device__ __forceinline__ void bf2f(uint32_t u, float& a, float& b) {
    union { uint32_t i; float f; } x;
    x.i = u << 16;          a = x.f;
    x.i = u & 0xffff0000u;  b = x.f;
}

__device__ __forceinline__ void gload16(const void* g, void* l) {
    __builtin_amdgcn_global_load_lds(
        (const __attribute__((address_space(1))) void*)g,
        (__attribute__((address_space(3))) void*)l, 16, 0, 0);
}

__device__ __forceinline__ void store_c(bf16* C, size_t off, float v) { C[off] = __float2bfloat16(v); }
__device__ __forceinline__ void store_c(float* C, size_t off, float v) { C[off] = v; }

// DPP butterfly add within rows of 16 lanes (VALU latency, no LDS)
template <int CTRL>
__device__ __forceinline__ float dppadd(float x) {
    int y = __builtin_amdgcn_update_dpp(0, __float_as_int(x), CTRL, 0xf, 0xf, true);
    return x + __int_as_float(y);
}
__device__ __forceinline__ float red16(float x) {
    x = dppadd<0xB1>(x);    // quad_perm [1,0,3,2]  : xor 1
    x = dppadd<0x4E>(x);    // quad_perm [2,3,0,1]  : xor 2
    x = dppadd<0x141>(x);   // row_half_mirror      : xor 4 (after lower stages)
    x = dppadd<0x140>(x);   // row_mirror           : xor 8 (after lower stages)
    return x;
}

// ---------- convert fp32 -> bf16 elementwise ----------
__global__ __launch_bounds__(256) void f2b_kernel(
    const float* __restrict__ in, bf16* __restrict__ out, int n)
{
    int i = blockIdx.x * 256 + threadIdx.x;
    if (i < n) out[i] = __float2bfloat16(in[i]);
}

// ---------- transpose+convert: in fp32 [R][C] -> out bf16 [C][R] ----------
__global__ __launch_bounds__(256) void transpose_kernel(
    const float* __restrict__ in, bf16* __restrict__ out, int R, int C)
{
    __shared__ bf16 tile[32][33];
    int c0 = blockIdx.x * 32, r0 = blockIdx.y * 32;
    int x = threadIdx.x;
    int y = threadIdx.y;
    #pragma unroll
    for (int i = y; i < 32; i += 8)
        tile[i][x] = __float2bfloat16(in[(size_t)(r0 + i) * C + c0 + x]);
    __syncthreads();
    #pragma unroll
    for (int i = y; i < 32; i += 8)
        out[(size_t)(c0 + i) * R + r0 + x] = tile[x][i];
}

// ---------- build [Wa|Wb|0] transposed: out bf16 [128][2048] ----------
__global__ __launch_bounds__(256) void build_wab_kernel(
    const float* __restrict__ Wa, const float* __restrict__ Wb, bf16* __restrict__ out)
{
    int k = blockIdx.x * 256 + threadIdx.x;
    int n = blockIdx.y;
    float v = 0.f;
    if (n < 32)      v = Wa[(size_t)k * 32 + n];
    else if (n < 64) v = Wb[(size_t)k * 32 + (n - 32)];
    out[(size_t)n * 2048 + k] = __float2bfloat16(v);
}

// ---------- MFMA GEMM: C[M,N] = A[M,K] * B^T (B given as [N,K]), bf16 in ----------
template <typename OutT>
__global__ __launch_bounds__(256) void gemm_bt_kernel(
    const bf16* __restrict__ A, const bf16* __restrict__ B, OutT* __restrict__ C,
    int M, int N, int K)
{
    __shared__ short sA[128 * 64];
    __shared__ short sB[128 * 64];
    const int tid  = threadIdx.x;
    const int w    = tid >> 6;
    const int lane = tid & 63;
    const int quad = lane >> 4;
    const int r    = lane & 15;
    const int wm   = w >> 1, wn = w & 1;
    const int bm   = blockIdx.x, bn = blockIdx.y;
    const int lrow = lane >> 3;
    const int lp   = lane & 7;
    const int lc   = lp ^ lrow;

    f32x4 acc[4][4] = {};

    const int nkb = K >> 6;
    for (int kb = 0; kb < nkb; ++kb) {
        __syncthreads();
        #pragma unroll
        for (int it = 0; it < 4; ++it) {
            int grp = w * 4 + it;
            int rr  = grp * 8 + lrow;
            const bf16* ga = A + (size_t)(bm * 128 + rr) * K + kb * 64 + lc * 8;
            gload16(ga, (void*)(sA + grp * 512));
            const bf16* gb = B + (size_t)(bn * 128 + rr) * K + kb * 64 + lc * 8;
            gload16(gb, (void*)(sB + grp * 512));
        }
        __syncthreads();

        #pragma unroll
        for (int kk = 0; kk < 2; ++kk) {
            short8 av[4], bv[4];
            #pragma unroll
            for (int i = 0; i < 4; ++i) {
                int p   = (kk * 4 + quad) ^ (r & 7);
                int row = wm * 64 + i * 16 + r;
                av[i] = *(const short8*)(sA + row * 64 + p * 8);
                int rowb = wn * 64 + i * 16 + r;
                bv[i] = *(const short8*)(sB + rowb * 64 + p * 8);
            }
            #pragma unroll
            for (int i = 0; i < 4; ++i)
                #pragma unroll
                for (int j = 0; j < 4; ++j)
                    acc[i][j] = __builtin_amdgcn_mfma_f32_16x16x32_bf16(
                        av[i], bv[j], acc[i][j], 0, 0, 0);
        }
    }

    #pragma unroll
    for (int i = 0; i < 4; ++i) {
        int row0 = bm * 128 + wm * 64 + i * 16 + quad * 4;
        #pragma unroll
        for (int j = 0; j < 4; ++j) {
            int col = bn * 128 + wn * 64 + j * 16 + r;
            #pragma unroll
            for (int e = 0; e < 4; ++e)
                store_c(C, (size_t)(row0 + e) * N + col, acc[i][j][e]);
        }
    }
}

// ---------- conv+silu+l2norm for q,k (fp32 out for the recurrence) ----------
__global__ __launch_bounds__(128) void conv_qk_kernel(
    const bf16* __restrict__ mixed, const float* __restrict__ cq,
    const float* __restrict__ ck, float* __restrict__ qn, float* __restrict__ kn)
{
    int t = blockIdx.x;
    int g = blockIdx.y;
    int d = threadIdx.x;
    int isq = (g < NKV) ? 1 : 0;
    int h   = isq ? g : g - NKV;
    int cl  = h * DKh + d;
    int c   = (isq ? 0 : 2048) + cl;
    const float* cw = isq ? cq : ck;
    float acc = 0.f;
    #pragma unroll
    for (int j = 0; j < 4; ++j) {
        int ts = t - 3 + j;
        if (ts >= 0)
            acc += __bfloat162float(mixed[(size_t)ts * 8192 + c]) * cw[cl * 4 + j];
    }
    float s = acc / (1.f + __expf(-acc));  // silu
    float ss = s * s;
    #pragma unroll
    for (int m = 1; m < 64; m <<= 1) ss += __shfl_xor(ss, m, 64);
    __shared__ float part[2];
    if ((threadIdx.x & 63) == 0) part[threadIdx.x >> 6] = ss;
    __syncthreads();
    float sum = part[0] + part[1];
    float rn = rsqrtf(sum + 1e-6f);
    float outv = s * rn;
    if (isq) outv *= 0.08838834764831845f;   // DK^-0.5 folded into q
    (isq ? qn : kn)[(size_t)t * 2048 + cl] = outv;
}

// ---------- conv+silu for v ----------
__global__ __launch_bounds__(256) void conv_v_kernel(
    const bf16* __restrict__ mixed, const float* __restrict__ cv, bf16* __restrict__ vv)
{
    int idx = blockIdx.x * 256 + threadIdx.x;
    int t = idx >> 12, c = idx & 4095;
    float acc = 0.f;
    #pragma unroll
    for (int j = 0; j < 4; ++j) {
        int ts = t - 3 + j;
        if (ts >= 0)
            acc += __bfloat162float(mixed[(size_t)ts * 8192 + 4096 + c]) * cv[c * 4 + j];
    }
    vv[idx] = __float2bfloat16(acc / (1.f + __expf(-acc)));
}

// ---------- gating ----------
__global__ __launch_bounds__(256) void gating_kernel(
    const float* __restrict__ ab, const float* __restrict__ dt_bias,
    const float* __restrict__ A_log, float* __restrict__ eg, float* __restrict__ beta)
{
    int i = blockIdx.x * 256 + threadIdx.x;
    int t = i >> 5, h = i & 31;
    float a  = ab[(size_t)t * 128 + h] + dt_bias[h];
    float sp = (a <= 20.f) ? log1pf(__expf(a)) : a;
    float gg = -__expf(A_log[h]) * sp;
    eg[i] = __expf(gg);
    float b = ab[(size_t)t * 128 + 32 + h];
    beta[i] = 1.f / (1.f + __expf(-b));
}

// ---------- gated delta-rule recurrence (DPP reductions + depth-2 prefetch) ----
// grid (32 heads, 8 dv-splits), block 256: thread = (dvl=tid>>4, dkg=tid&15)
// owns S[dkg*8..+8][dv] in registers; 16-lane DPP butterfly for kv and o.
__device__ __forceinline__ void gdn_step(
    float S[8], const float kf[8], const float qf[8],
    float vc, float egt, float bt, bf16* optr, bool writer)
{
    float t0[8];
    #pragma unroll
    for (int j = 0; j < 8; ++j) t0[j] = S[j] * egt;
    float p0 = t0[0] * kf[0], p1 = t0[1] * kf[1], p2 = t0[2] * kf[2], p3 = t0[3] * kf[3];
    p0 = fmaf(t0[4], kf[4], p0); p1 = fmaf(t0[5], kf[5], p1);
    p2 = fmaf(t0[6], kf[6], p2); p3 = fmaf(t0[7], kf[7], p3);
    float kv = red16((p0 + p1) + (p2 + p3));
    float dvv = bt * (vc - kv);
    #pragma unroll
    for (int j = 0; j < 8; ++j) S[j] = fmaf(kf[j], dvv, t0[j]);
    float o0 = qf[0] * S[0], o1 = qf[1] * S[1], o2 = qf[2] * S[2], o3 = qf[3] * S[3];
    o0 = fmaf(qf[4], S[4], o0); o1 = fmaf(qf[5], S[5], o1);
    o2 = fmaf(qf[6], S[6], o2); o3 = fmaf(qf[7], S[7], o3);
    float op = red16((o0 + o1) + (o2 + o3));
    if (writer) *optr = __float2bfloat16(op);
}

__global__ __launch_bounds__(256) void recur_kernel(
    const float* __restrict__ qn, const float* __restrict__ kn, const bf16* __restrict__ vv,
    const float* __restrict__ egb, const float* __restrict__ betab, bf16* __restrict__ o)
{
    int h   = blockIdx.x;
    int sp  = blockIdx.y;
    int tid = threadIdx.x;
    int dvl = tid >> 4;
    int dkg = tid & 15;
    int dv  = sp * 16 + dvl;
    int hkv = h >> 1;                       // GQA repeat-interleave
    bool writer = (dkg == 0);

    const float* kp = kn + hkv * DKh + dkg * 8;
    const float* qp = qn + hkv * DKh + dkg * 8;
    const bf16*  vp = vv + h * DVh + dv;
    const float* ep = egb + h;
    const float* bp = betab + h;
    bf16* optr = o + h * DVh + dv;

    float S[8] = {0.f, 0.f, 0.f, 0.f, 0.f, 0.f, 0.f, 0.f};

    // depth-2 prefetch slots (reads up to 2 rows past each array end land in
    // the adjacent workspace allocation — see ws layout; values unused).
    float4 k0a = *(const float4*)(kp),        k0b = *(const float4*)(kp + 4);
    float4 q0a = *(const float4*)(qp),        q0b = *(const float4*)(qp + 4);
    float  v0  = __bfloat162float(vp[0]);
    float  e0  = ep[0], b0 = bp[0];
    float4 k1a = *(const float4*)(kp + 2048), k1b = *(const float4*)(kp + 2052);
    float4 q1a = *(const float4*)(qp + 2048), q1b = *(const float4*)(qp + 2052);
    float  v1  = __bfloat162float(vp[4096]);
    float  e1  = ep[32], b1 = bp[32];

    #pragma unroll 1
    for (int t = 0; t < T_TOK; t += 2) {
        {   // step t (slot 0)
            float kf[8] = {k0a.x, k0a.y, k0a.z, k0a.w, k0b.x, k0b.y, k0b.z, k0b.w};
            float qf[8] = {q0a.x, q0a.y, q0a.z, q0a.w, q0b.x, q0b.y, q0b.z, q0b.w};
            float vc = v0, egt = e0, bt = b0;
            size_t r = (size_t)(t + 2);
            k0a = *(const float4*)(kp + r * 2048); k0b = *(const float4*)(kp + r * 2048 + 4);
            q0a = *(const float4*)(qp + r * 2048); q0b = *(const float4*)(qp + r * 2048 + 4);
            v0  = __bfloat162float(vp[r * 4096]);
            e0  = ep[r * 32]; b0 = bp[r * 32];
            gdn_step(S, kf, qf, vc, egt, bt, optr + (size_t)t * 4096, writer);
        }
        {   // step t+1 (slot 1)
            float kf[8] = {k1a.x, k1a.y, k1a.z, k1a.w, k1b.x, k1b.y, k1b.z, k1b.w};
            float qf[8] = {q1a.x, q1a.y, q1a.z, q1a.w, q1b.x, q1b.y, q1b.z, q1b.w};
            float vc = v1, egt = e1, bt = b1;
            size_t r = (size_t)(t + 3);
            k1a = *(const float4*)(kp + r * 2048); k1b = *(const float4*)(kp + r * 2048 + 4);
            q1a = *(const float4*)(qp + r * 2048); q1b = *(const float4*)(qp + r * 2048 + 4);
            v1  = __bfloat162float(vp[r * 4096]);
            e1  = ep[r * 32]; b1 = bp[r * 32];
            gdn_step(S, kf, qf, vc, egt, bt, optr + (size_t)(t + 1) * 4096, writer);
        }
    }
}

// ---------- gated RMSNorm ----------
__global__ __launch_bounds__(256) void normgate_kernel(
    const bf16* __restrict__ o, const bf16* __restrict__ gate,
    const float* __restrict__ w, bf16* __restrict__ og)
{
    int grp  = blockIdx.x * 4 + (threadIdx.x >> 6);
    int lane = threadIdx.x & 63;
    int t = grp >> 5, h = grp & 31;
    size_t base = (size_t)t * 4096 + h * DVh;
    uint32_t uo = *(const uint32_t*)(o + base + lane * 2);
    float a, b; bf2f(uo, a, b);
    float ss = a * a + b * b;
    #pragma unroll
    for (int m = 1; m < 64; m <<= 1) ss += __shfl_xor(ss, m, 64);
    float rn = rsqrtf(ss * (1.f / 128.f) + 1e-5f);
    uint32_t ug = *(const uint32_t*)(gate + base + lane * 2);
    float ga, gb; bf2f(ug, ga, gb);
    float wa = w[lane * 2], wb = w[lane * 2 + 1];
    float oa = a * rn * wa * (ga / (1.f + __expf(-ga)));
    float ob = b * rn * wb * (gb / (1.f + __expf(-gb)));
    og[base + lane * 2]     = __float2bfloat16(oa);
    og[base + lane * 2 + 1] = __float2bfloat16(ob);
}

// ---------- launch ----------
extern "C" void kernel_launch(void* const* d_in, const int* in_sizes, int n_in,
                              void* d_out, int out_size, void* d_ws, size_t ws_size,
                              hipStream_t stream)
{
    const float* h       = (const float*)d_in[0];
    const float* Wq      = (const float*)d_in[1];
    const float* Wk      = (const float*)d_in[2];
    const float* Wv      = (const float*)d_in[3];
    const float* Wa      = (const float*)d_in[4];
    const float* Wb      = (const float*)d_in[5];
    const float* Wg      = (const float*)d_in[6];
    const float* conv_q  = (const float*)d_in[7];
    const float* conv_k  = (const float*)d_in[8];
    const float* conv_v  = (const float*)d_in[9];
    const float* dt_bias = (const float*)d_in[10];
    const float* A_log   = (const float*)d_in[11];
    const float* onw     = (const float*)d_in[12];
    const float* Wo      = (const float*)d_in[13];
    float* out = (float*)d_out;

    char* ws = (char*)d_ws;
    bf16*  WqkvT = (bf16*)ws;   ws += (size_t)8192 * 2048 * 2;   // 33.5 MB
    bf16*  WgT   = (bf16*)ws;   ws += (size_t)4096 * 2048 * 2;   // 16.8 MB (reused as qnb)
    bf16*  WoT   = (bf16*)ws;   ws += (size_t)2048 * 4096 * 2;   // 16.8 MB
    bf16*  WabT  = (bf16*)ws;   ws += (size_t)128 * 2048 * 2;
    bf16*  hb    = (bf16*)ws;   ws += (size_t)2048 * 2048 * 2;
    bf16*  mixed = (bf16*)ws;   ws += (size_t)2048 * 8192 * 2;   // 33.5 MB
    float* ab    = (float*)ws;  ws += (size_t)2048 * 128 * 4;
    float* knb   = (float*)ws;  ws += (size_t)2048 * 2048 * 4;   // 16.8 MB fp32
    bf16*  vvb   = (bf16*)ws;   ws += (size_t)2048 * 4096 * 2;   // 16.8 MB
    float* eg    = (float*)ws;  ws += (size_t)2048 * 32 * 4;
    float* beta  = (float*)ws;  ws += (size_t)2048 * 32 * 4;
    ws += 8192;                                                  // OOB-prefetch pad
    // aliases over dead regions (stream-ordered lifetimes):
    float* qnb = (float*)WgT;                      // WgT dead after gate GEMM; fp32 16.8 MB fits exactly
    bf16*  ob   = WqkvT;                           // WqkvT dead after qkv GEMM
    bf16*  gate = WqkvT + (size_t)2048 * 4096;     // second half of WqkvT region
    bf16*  og   = mixed;                           // mixed dead after conv kernels

    dim3 tb(32, 8);
    transpose_kernel<<<dim3(64, 64),  tb, 0, stream>>>(Wq, WqkvT,                       2048, 2048);
    transpose_kernel<<<dim3(64, 64),  tb, 0, stream>>>(Wk, WqkvT + (size_t)2048 * 2048, 2048, 2048);
    transpose_kernel<<<dim3(128, 64), tb, 0, stream>>>(Wv, WqkvT + (size_t)4096 * 2048, 2048, 4096);
    transpose_kernel<<<dim3(128, 64), tb, 0, stream>>>(Wg, WgT,                         2048, 4096);
    transpose_kernel<<<dim3(64, 128), tb, 0, stream>>>(Wo, WoT,                         4096, 2048);
    build_wab_kernel<<<dim3(8, 128), 256, 0, stream>>>(Wa, Wb, WabT);
    f2b_kernel<<<16384, 256, 0, stream>>>(h, hb, 2048 * 2048);

    gemm_bt_kernel<bf16> <<<dim3(16, 64), 256, 0, stream>>>(hb, WqkvT, mixed, 2048, 8192, 2048);
    gemm_bt_kernel<float><<<dim3(16, 1),  256, 0, stream>>>(hb, WabT,  ab,    2048, 128,  2048);
    gemm_bt_kernel<bf16> <<<dim3(16, 32), 256, 0, stream>>>(hb, WgT,   gate,  2048, 4096, 2048);

    conv_qk_kernel<<<dim3(2048, 32), 128, 0, stream>>>(mixed, conv_q, conv_k, qnb, knb);
    conv_v_kernel<<<32768, 256, 0, stream>>>(mixed, conv_v, vvb);
    gating_kernel<<<256, 256, 0, stream>>>(ab, dt_bias, A_log, eg, beta);

    recur_kernel<<<dim3(32, 8), 256, 0, stream>>>(qnb, knb, vvb, eg, beta, ob);
    normgate_kernel<<<16384, 256, 0, stream>>>(ob, gate, onw, og);

    gemm_bt_kernel<float><<<dim3(16, 16), 256, 0, stream>>>(og, WoT, out, 2048, 2048, 4096);
}

// Round 4
// 1032.311 us; speedup vs baseline: 1.5778x; 1.2013x over previous
//
#include <hip/hip_runtime.h>
#include <hip/hip_bf16.h>
#include <stdint.h>
#include <stddef.h>

using bf16 = __hip_bfloat16;
typedef __attribute__((ext_vector_type(8))) short short8;   // 8 bf16 (4 VGPRs)
typedef __attribute__((ext_vector_type(4))) float f32x4;

#define T_TOK 2048
#define HD    2048
#define NH    32
#define NKV   16
#define DKh   128
#define DVh   128

// ---------- helpers ----------
__device__ __forceinline__ void bf2f(uint32_t u, float& a, float& b) {
    union { uint32_t i; float f; } x;
    x.i = u << 16;          a = x.f;
    x.i = u & 0xffff0000u;  b = x.f;
}

__device__ __forceinline__ void gload16(const void* g, void* l) {
    __builtin_amdgcn_global_load_lds(
        (const __attribute__((address_space(1))) void*)g,
        (__attribute__((address_space(3))) void*)l, 16, 0, 0);
}

__device__ __forceinline__ void store_c(bf16* C, size_t off, float v) { C[off] = __float2bfloat16(v); }
__device__ __forceinline__ void store_c(float* C, size_t off, float v) { C[off] = v; }

// DPP butterfly add within rows of 16 lanes (VALU latency, no LDS)
template <int CTRL>
__device__ __forceinline__ float dppadd(float x) {
    int y = __builtin_amdgcn_update_dpp(0, __float_as_int(x), CTRL, 0xf, 0xf, true);
    return x + __int_as_float(y);
}
__device__ __forceinline__ float red16(float x) {
    x = dppadd<0xB1>(x);    // quad_perm [1,0,3,2]  : xor 1
    x = dppadd<0x4E>(x);    // quad_perm [2,3,0,1]  : xor 2
    x = dppadd<0x141>(x);   // row_half_mirror      : xor 4
    x = dppadd<0x140>(x);   // row_mirror           : xor 8
    return x;
}

// ---------- convert fp32 -> bf16 elementwise ----------
__global__ __launch_bounds__(256) void f2b_kernel(
    const float* __restrict__ in, bf16* __restrict__ out, int n)
{
    int i = blockIdx.x * 256 + threadIdx.x;
    if (i < n) out[i] = __float2bfloat16(in[i]);
}

// ---------- transpose+convert: in fp32 [R][C] -> out bf16 [C][R] ----------
__global__ __launch_bounds__(256) void transpose_kernel(
    const float* __restrict__ in, bf16* __restrict__ out, int R, int C)
{
    __shared__ bf16 tile[32][33];
    int c0 = blockIdx.x * 32, r0 = blockIdx.y * 32;
    int x = threadIdx.x;
    int y = threadIdx.y;
    #pragma unroll
    for (int i = y; i < 32; i += 8)
        tile[i][x] = __float2bfloat16(in[(size_t)(r0 + i) * C + c0 + x]);
    __syncthreads();
    #pragma unroll
    for (int i = y; i < 32; i += 8)
        out[(size_t)(c0 + i) * R + r0 + x] = tile[x][i];
}

// ---------- build [Wa|Wb|0] transposed: out bf16 [128][2048] ----------
__global__ __launch_bounds__(256) void build_wab_kernel(
    const float* __restrict__ Wa, const float* __restrict__ Wb, bf16* __restrict__ out)
{
    int k = blockIdx.x * 256 + threadIdx.x;
    int n = blockIdx.y;
    float v = 0.f;
    if (n < 32)      v = Wa[(size_t)k * 32 + n];
    else if (n < 64) v = Wb[(size_t)k * 32 + (n - 32)];
    out[(size_t)n * 2048 + k] = __float2bfloat16(v);
}

// ---------- MFMA GEMM: C[M,N] = A[M,K] * B^T (B given as [N,K]), bf16 in ----------
template <typename OutT>
__global__ __launch_bounds__(256) void gemm_bt_kernel(
    const bf16* __restrict__ A, const bf16* __restrict__ B, OutT* __restrict__ C,
    int M, int N, int K)
{
    __shared__ short sA[128 * 64];
    __shared__ short sB[128 * 64];
    const int tid  = threadIdx.x;
    const int w    = tid >> 6;
    const int lane = tid & 63;
    const int quad = lane >> 4;
    const int r    = lane & 15;
    const int wm   = w >> 1, wn = w & 1;
    const int bm   = blockIdx.x, bn = blockIdx.y;
    const int lrow = lane >> 3;
    const int lp   = lane & 7;
    const int lc   = lp ^ lrow;

    f32x4 acc[4][4] = {};

    const int nkb = K >> 6;
    for (int kb = 0; kb < nkb; ++kb) {
        __syncthreads();
        #pragma unroll
        for (int it = 0; it < 4; ++it) {
            int grp = w * 4 + it;
            int rr  = grp * 8 + lrow;
            const bf16* ga = A + (size_t)(bm * 128 + rr) * K + kb * 64 + lc * 8;
            gload16(ga, (void*)(sA + grp * 512));
            const bf16* gb = B + (size_t)(bn * 128 + rr) * K + kb * 64 + lc * 8;
            gload16(gb, (void*)(sB + grp * 512));
        }
        __syncthreads();

        #pragma unroll
        for (int kk = 0; kk < 2; ++kk) {
            short8 av[4], bv[4];
            #pragma unroll
            for (int i = 0; i < 4; ++i) {
                int p   = (kk * 4 + quad) ^ (r & 7);
                int row = wm * 64 + i * 16 + r;
                av[i] = *(const short8*)(sA + row * 64 + p * 8);
                int rowb = wn * 64 + i * 16 + r;
                bv[i] = *(const short8*)(sB + rowb * 64 + p * 8);
            }
            #pragma unroll
            for (int i = 0; i < 4; ++i)
                #pragma unroll
                for (int j = 0; j < 4; ++j)
                    acc[i][j] = __builtin_amdgcn_mfma_f32_16x16x32_bf16(
                        av[i], bv[j], acc[i][j], 0, 0, 0);
        }
    }

    #pragma unroll
    for (int i = 0; i < 4; ++i) {
        int row0 = bm * 128 + wm * 64 + i * 16 + quad * 4;
        #pragma unroll
        for (int j = 0; j < 4; ++j) {
            int col = bn * 128 + wn * 64 + j * 16 + r;
            #pragma unroll
            for (int e = 0; e < 4; ++e)
                store_c(C, (size_t)(row0 + e) * N + col, acc[i][j][e]);
        }
    }
}

// ---------- conv+silu+l2norm for q,k (fp32 out for the recurrence) ----------
__global__ __launch_bounds__(128) void conv_qk_kernel(
    const bf16* __restrict__ mixed, const float* __restrict__ cq,
    const float* __restrict__ ck, float* __restrict__ qn, float* __restrict__ kn)
{
    int t = blockIdx.x;
    int g = blockIdx.y;
    int d = threadIdx.x;
    int isq = (g < NKV) ? 1 : 0;
    int h   = isq ? g : g - NKV;
    int cl  = h * DKh + d;
    int c   = (isq ? 0 : 2048) + cl;
    const float* cw = isq ? cq : ck;
    float acc = 0.f;
    #pragma unroll
    for (int j = 0; j < 4; ++j) {
        int ts = t - 3 + j;
        if (ts >= 0)
            acc += __bfloat162float(mixed[(size_t)ts * 8192 + c]) * cw[cl * 4 + j];
    }
    float s = acc / (1.f + __expf(-acc));  // silu
    float ss = s * s;
    #pragma unroll
    for (int m = 1; m < 64; m <<= 1) ss += __shfl_xor(ss, m, 64);
    __shared__ float part[2];
    if ((threadIdx.x & 63) == 0) part[threadIdx.x >> 6] = ss;
    __syncthreads();
    float sum = part[0] + part[1];
    float rn = rsqrtf(sum + 1e-6f);
    float outv = s * rn;
    if (isq) outv *= 0.08838834764831845f;   // DK^-0.5 folded into q
    (isq ? qn : kn)[(size_t)t * 2048 + cl] = outv;
}

// ---------- conv+silu for v ----------
__global__ __launch_bounds__(256) void conv_v_kernel(
    const bf16* __restrict__ mixed, const float* __restrict__ cv, bf16* __restrict__ vv)
{
    int idx = blockIdx.x * 256 + threadIdx.x;
    int t = idx >> 12, c = idx & 4095;
    float acc = 0.f;
    #pragma unroll
    for (int j = 0; j < 4; ++j) {
        int ts = t - 3 + j;
        if (ts >= 0)
            acc += __bfloat162float(mixed[(size_t)ts * 8192 + 4096 + c]) * cv[c * 4 + j];
    }
    vv[idx] = __float2bfloat16(acc / (1.f + __expf(-acc)));
}

// ---------- gating ----------
__global__ __launch_bounds__(256) void gating_kernel(
    const float* __restrict__ ab, const float* __restrict__ dt_bias,
    const float* __restrict__ A_log, float* __restrict__ eg, float* __restrict__ beta)
{
    int i = blockIdx.x * 256 + threadIdx.x;
    int t = i >> 5, h = i & 31;
    float a  = ab[(size_t)t * 128 + h] + dt_bias[h];
    float sp = (a <= 20.f) ? log1pf(__expf(a)) : a;
    float gg = -__expf(A_log[h]) * sp;
    eg[i] = __expf(gg);
    float b = ab[(size_t)t * 128 + 32 + h];
    beta[i] = 1.f / (1.f + __expf(-b));
}

// ---------- gated delta-rule recurrence (DPP reductions + depth-8 prefetch) ----
// grid (32 heads, 8 dv-splits), block 256: thread = (dvl=tid>>4, dkg=tid&15)
// owns S[dkg*8..+8][dv] in registers; 16-lane DPP butterfly for kv and o.
// Depth-8 register prefetch: equilibrium T_step = max(compute, HBM_latency/8).
__device__ __forceinline__ void gdn_step(
    float S[8], const float kf[8], const float qf[8],
    float vc, float egt, float bt, bf16* optr, bool writer)
{
    float t0[8];
    #pragma unroll
    for (int j = 0; j < 8; ++j) t0[j] = S[j] * egt;
    float p0 = t0[0] * kf[0], p1 = t0[1] * kf[1], p2 = t0[2] * kf[2], p3 = t0[3] * kf[3];
    p0 = fmaf(t0[4], kf[4], p0); p1 = fmaf(t0[5], kf[5], p1);
    p2 = fmaf(t0[6], kf[6], p2); p3 = fmaf(t0[7], kf[7], p3);
    float kv = red16((p0 + p1) + (p2 + p3));
    float dvv = bt * (vc - kv);
    #pragma unroll
    for (int j = 0; j < 8; ++j) S[j] = fmaf(kf[j], dvv, t0[j]);
    float o0 = qf[0] * S[0], o1 = qf[1] * S[1], o2 = qf[2] * S[2], o3 = qf[3] * S[3];
    o0 = fmaf(qf[4], S[4], o0); o1 = fmaf(qf[5], S[5], o1);
    o2 = fmaf(qf[6], S[6], o2); o3 = fmaf(qf[7], S[7], o3);
    float op = red16((o0 + o1) + (o2 + o3));
    if (writer) *optr = __float2bfloat16(op);
}

#define PF_DEPTH 8

__global__ __launch_bounds__(256) void recur_kernel(
    const float* __restrict__ qn, const float* __restrict__ kn, const bf16* __restrict__ vv,
    const float* __restrict__ egb, const float* __restrict__ betab, bf16* __restrict__ o)
{
    int h   = blockIdx.x;
    int sp  = blockIdx.y;
    int tid = threadIdx.x;
    int dvl = tid >> 4;
    int dkg = tid & 15;
    int dv  = sp * 16 + dvl;
    int hkv = h >> 1;                       // GQA repeat-interleave
    bool writer = (dkg == 0);

    const float* kp = kn + hkv * DKh + dkg * 8;
    const float* qp = qn + hkv * DKh + dkg * 8;
    const bf16*  vp = vv + h * DVh + dv;
    const float* ep = egb + h;
    const float* bp = betab + h;
    bf16* optr = o + h * DVh + dv;

    float S[8] = {0.f, 0.f, 0.f, 0.f, 0.f, 0.f, 0.f, 0.f};

    // prefetch slots (rows t .. t+7). OOB reads (up to 8 rows past each array
    // end) land in the adjacent workspace allocation / pad; values unused.
    float4 ka[PF_DEPTH], kb[PF_DEPTH], qa[PF_DEPTH], qb[PF_DEPTH];
    float  vs[PF_DEPTH], es[PF_DEPTH], bs[PF_DEPTH];
    #pragma unroll
    for (int s = 0; s < PF_DEPTH; ++s) {
        ka[s] = *(const float4*)(kp + (size_t)s * 2048);
        kb[s] = *(const float4*)(kp + (size_t)s * 2048 + 4);
        qa[s] = *(const float4*)(qp + (size_t)s * 2048);
        qb[s] = *(const float4*)(qp + (size_t)s * 2048 + 4);
        vs[s] = __bfloat162float(vp[(size_t)s * 4096]);
        es[s] = ep[(size_t)s * 32];
        bs[s] = bp[(size_t)s * 32];
    }
    const float* kl = kp + (size_t)PF_DEPTH * 2048;
    const float* ql = qp + (size_t)PF_DEPTH * 2048;
    const bf16*  vl = vp + (size_t)PF_DEPTH * 4096;
    const float* el = ep + (size_t)PF_DEPTH * 32;
    const float* bl = bp + (size_t)PF_DEPTH * 32;

    #pragma unroll 1
    for (int t = 0; t < T_TOK; t += PF_DEPTH) {
        #pragma unroll
        for (int s = 0; s < PF_DEPTH; ++s) {
            float kf[8] = {ka[s].x, ka[s].y, ka[s].z, ka[s].w,
                           kb[s].x, kb[s].y, kb[s].z, kb[s].w};
            float qf[8] = {qa[s].x, qa[s].y, qa[s].z, qa[s].w,
                           qb[s].x, qb[s].y, qb[s].z, qb[s].w};
            float vc = vs[s], egt = es[s], bt = bs[s];
            // refill slot s with row t+s+PF_DEPTH (pad-covered when OOB)
            ka[s] = *(const float4*)(kl + (size_t)s * 2048);
            kb[s] = *(const float4*)(kl + (size_t)s * 2048 + 4);
            qa[s] = *(const float4*)(ql + (size_t)s * 2048);
            qb[s] = *(const float4*)(ql + (size_t)s * 2048 + 4);
            vs[s] = __bfloat162float(vl[(size_t)s * 4096]);
            es[s] = el[(size_t)s * 32];
            bs[s] = bl[(size_t)s * 32];
            gdn_step(S, kf, qf, vc, egt, bt, optr + (size_t)(t + s) * 4096, writer);
        }
        kl += (size_t)PF_DEPTH * 2048;
        ql += (size_t)PF_DEPTH * 2048;
        vl += (size_t)PF_DEPTH * 4096;
        el += PF_DEPTH * 32;
        bl += PF_DEPTH * 32;
    }
}

// ---------- gated RMSNorm ----------
__global__ __launch_bounds__(256) void normgate_kernel(
    const bf16* __restrict__ o, const bf16* __restrict__ gate,
    const float* __restrict__ w, bf16* __restrict__ og)
{
    int grp  = blockIdx.x * 4 + (threadIdx.x >> 6);
    int lane = threadIdx.x & 63;
    int t = grp >> 5, h = grp & 31;
    size_t base = (size_t)t * 4096 + h * DVh;
    uint32_t uo = *(const uint32_t*)(o + base + lane * 2);
    float a, b; bf2f(uo, a, b);
    float ss = a * a + b * b;
    #pragma unroll
    for (int m = 1; m < 64; m <<= 1) ss += __shfl_xor(ss, m, 64);
    float rn = rsqrtf(ss * (1.f / 128.f) + 1e-5f);
    uint32_t ug = *(const uint32_t*)(gate + base + lane * 2);
    float ga, gb; bf2f(ug, ga, gb);
    float wa = w[lane * 2], wb = w[lane * 2 + 1];
    float oa = a * rn * wa * (ga / (1.f + __expf(-ga)));
    float ob = b * rn * wb * (gb / (1.f + __expf(-gb)));
    og[base + lane * 2]     = __float2bfloat16(oa);
    og[base + lane * 2 + 1] = __float2bfloat16(ob);
}

// ---------- launch ----------
extern "C" void kernel_launch(void* const* d_in, const int* in_sizes, int n_in,
                              void* d_out, int out_size, void* d_ws, size_t ws_size,
                              hipStream_t stream)
{
    const float* h       = (const float*)d_in[0];
    const float* Wq      = (const float*)d_in[1];
    const float* Wk      = (const float*)d_in[2];
    const float* Wv      = (const float*)d_in[3];
    const float* Wa      = (const float*)d_in[4];
    const float* Wb      = (const float*)d_in[5];
    const float* Wg      = (const float*)d_in[6];
    const float* conv_q  = (const float*)d_in[7];
    const float* conv_k  = (const float*)d_in[8];
    const float* conv_v  = (const float*)d_in[9];
    const float* dt_bias = (const float*)d_in[10];
    const float* A_log   = (const float*)d_in[11];
    const float* onw     = (const float*)d_in[12];
    const float* Wo      = (const float*)d_in[13];
    float* out = (float*)d_out;

    char* ws = (char*)d_ws;
    bf16*  WqkvT = (bf16*)ws;   ws += (size_t)8192 * 2048 * 2;   // 33.5 MB
    bf16*  WgT   = (bf16*)ws;   ws += (size_t)4096 * 2048 * 2;   // 16.8 MB (reused as qnb)
    bf16*  WoT   = (bf16*)ws;   ws += (size_t)2048 * 4096 * 2;   // 16.8 MB
    bf16*  WabT  = (bf16*)ws;   ws += (size_t)128 * 2048 * 2;
    bf16*  hb    = (bf16*)ws;   ws += (size_t)2048 * 2048 * 2;
    bf16*  mixed = (bf16*)ws;   ws += (size_t)2048 * 8192 * 2;   // 33.5 MB
    float* ab    = (float*)ws;  ws += (size_t)2048 * 128 * 4;
    float* knb   = (float*)ws;  ws += (size_t)2048 * 2048 * 4;   // 16.8 MB fp32
    bf16*  vvb   = (bf16*)ws;   ws += (size_t)2048 * 4096 * 2;   // 16.8 MB
    float* eg    = (float*)ws;  ws += (size_t)2048 * 32 * 4;
    float* beta  = (float*)ws;  ws += (size_t)2048 * 32 * 4;
    ws += 32768;                                                 // OOB-prefetch pad
    // aliases over dead regions (stream-ordered lifetimes):
    float* qnb = (float*)WgT;                      // WgT dead after gate GEMM
    bf16*  ob   = WqkvT;                           // WqkvT dead after qkv GEMM
    bf16*  gate = WqkvT + (size_t)2048 * 4096;     // second half of WqkvT region
    bf16*  og   = mixed;                           // mixed dead after conv kernels

    dim3 tb(32, 8);
    transpose_kernel<<<dim3(64, 64),  tb, 0, stream>>>(Wq, WqkvT,                       2048, 2048);
    transpose_kernel<<<dim3(64, 64),  tb, 0, stream>>>(Wk, WqkvT + (size_t)2048 * 2048, 2048, 2048);
    transpose_kernel<<<dim3(128, 64), tb, 0, stream>>>(Wv, WqkvT + (size_t)4096 * 2048, 2048, 4096);
    transpose_kernel<<<dim3(128, 64), tb, 0, stream>>>(Wg, WgT,                         2048, 4096);
    transpose_kernel<<<dim3(64, 128), tb, 0, stream>>>(Wo, WoT,                         4096, 2048);
    build_wab_kernel<<<dim3(8, 128), 256, 0, stream>>>(Wa, Wb, WabT);
    f2b_kernel<<<16384, 256, 0, stream>>>(h, hb, 2048 * 2048);

    gemm_bt_kernel<bf16> <<<dim3(16, 64), 256, 0, stream>>>(hb, WqkvT, mixed, 2048, 8192, 2048);
    gemm_bt_kernel<float><<<dim3(16, 1),  256, 0, stream>>>(hb, WabT,  ab,    2048, 128,  2048);
    gemm_bt_kernel<bf16> <<<dim3(16, 32), 256, 0, stream>>>(hb, WgT,   gate,  2048, 4096, 2048);

    conv_qk_kernel<<<dim3(2048, 32), 128, 0, stream>>>(mixed, conv_q, conv_k, qnb, knb);
    conv_v_kernel<<<32768, 256, 0, stream>>>(mixed, conv_v, vvb);
    gating_kernel<<<256, 256, 0, stream>>>(ab, dt_bias, A_log, eg, beta);

    recur_kernel<<<dim3(32, 8), 256, 0, stream>>>(qnb, knb, vvb, eg, beta, ob);
    normgate_kernel<<<16384, 256, 0, stream>>>(ob, gate, onw, og);

    gemm_bt_kernel<float><<<dim3(16, 16), 256, 0, stream>>>(og, WoT, out, 2048, 2048, 4096);
}